// Round 1
// baseline (772.144 us; speedup 1.0000x reference)
//
#include <hip/hip_runtime.h>

// Problem constants (fixed by setup_inputs): (B,D,H,W) = (2,256,256,128), fp32.
#define LAMB 0.01f
constexpr int Bc = 2, Dc = 256, Hc = 256, Wc = 128;
constexpr int HW  = Hc * Wc;          // 32768  (stride of D)
constexpr int NELEM_I = Bc * Dc * Hc * Wc; // 16,777,216 (fits in int)

__device__ __forceinline__ float clipf(float x, float s) {
    return fminf(fmaxf(x, -s), s);
}

// extrapolated dual update: pnew = clip(pold - dz, +-sg); return pnew + nt*(pnew - pold)
__device__ __forceinline__ float dual_up(float pold, float dz, float sg, float ntc) {
    float pn = clipf(pold - dz, sg);
    return pn + ntc * (pn - pold);
}

// ---------------- Fused per-cascade kernel (needs ping-pong dual buffers) ----
// Each thread: computes z at 7-pt stencil on the fly, the extrapolated duals at
// its own site and at the -1 neighbor per axis, writes t_new (+ duals, + copy).
template <bool FIRST, bool WRITE_PQS, bool WRITE_COPY>
__global__ __launch_bounds__(256) void cascade_fused(
    const float* __restrict__ t_in, const float* __restrict__ sino,
    const float* __restrict__ p_in, const float* __restrict__ q_in,
    const float* __restrict__ s_in,
    float* __restrict__ p_out, float* __restrict__ q_out, float* __restrict__ s_out,
    float* __restrict__ t_out, float* __restrict__ copy_out,
    const float* __restrict__ sigma, const float* __restrict__ nt, int c)
{
    const int idx = blockIdx.x * blockDim.x + threadIdx.x;
    if (idx >= NELEM_I) return;

    const int w = idx & (Wc - 1);
    const int h = (idx >> 7) & (Hc - 1);
    const int d = (idx >> 15) & (Dc - 1);

    const float s0 = sigma[0], s1 = sigma[1], s2 = sigma[2], s3 = sigma[3];
    const float ntc = nt[c];

    const float tc = t_in[idx];
    const float zc = tc + LAMB * (sino[idx] - tc);
    if (WRITE_COPY) copy_out[idx] = tc;

    auto Z = [&](int i) { float tv = t_in[i]; return tv + LAMB * (sino[i] - tv); };

    // ---- axis D (axis=1) ----
    float pold_c = FIRST ? 0.f : p_in[idx];
    float pc = dual_up(pold_c, (d < Dc - 1) ? (Z(idx + HW) - zc) : 0.f, s0, ntc);
    float pm = 0.f;
    if (d > 0) {
        float pold_m = FIRST ? 0.f : p_in[idx - HW];
        pm = dual_up(pold_m, zc - Z(idx - HW), s0, ntc);  // (d-1) < Dc-1 always
    }
    const float dt1 = pm - ((d < Dc - 1) ? pc : 0.f);

    // ---- axis H (axis=2) ----
    float qold_c = FIRST ? 0.f : q_in[idx];
    float qc = dual_up(qold_c, (h < Hc - 1) ? (Z(idx + Wc) - zc) : 0.f, s1, ntc);
    float qm = 0.f;
    if (h > 0) {
        float qold_m = FIRST ? 0.f : q_in[idx - Wc];
        qm = dual_up(qold_m, zc - Z(idx - Wc), s1, ntc);
    }
    const float dt2 = qm - ((h < Hc - 1) ? qc : 0.f);

    // ---- axis W (axis=3) ----
    float sold_c = FIRST ? 0.f : s_in[idx];
    float sc = dual_up(sold_c, (w < Wc - 1) ? (Z(idx + 1) - zc) : 0.f, s2, ntc);
    float sm = 0.f;
    if (w > 0) {
        float sold_m = FIRST ? 0.f : s_in[idx - 1];
        sm = dual_up(sold_m, zc - Z(idx - 1), s2, ntc);
    }
    const float dt3 = sm - ((w < Wc - 1) ? sc : 0.f);

    if (WRITE_PQS) { p_out[idx] = pc; q_out[idx] = qc; s_out[idx] = sc; }
    t_out[idx] = dt1 + dt2 + dt3 + clipf(zc, s3);
}

// ---------------- Fallback split path (in-place duals, 3 arrays of ws) -------
template <bool FIRST, bool WRITE_COPY>
__global__ __launch_bounds__(256) void dual_kernel(
    const float* __restrict__ t_in, const float* __restrict__ sino,
    float* p, float* q, float* s,
    float* __restrict__ copy_out,
    const float* __restrict__ sigma, const float* __restrict__ nt, int c)
{
    const int idx = blockIdx.x * blockDim.x + threadIdx.x;
    if (idx >= NELEM_I) return;
    const int w = idx & (Wc - 1);
    const int h = (idx >> 7) & (Hc - 1);
    const int d = (idx >> 15) & (Dc - 1);

    const float s0 = sigma[0], s1 = sigma[1], s2 = sigma[2];
    const float ntc = nt[c];

    const float tc = t_in[idx];
    const float zc = tc + LAMB * (sino[idx] - tc);
    if (WRITE_COPY) copy_out[idx] = tc;
    auto Z = [&](int i) { float tv = t_in[i]; return tv + LAMB * (sino[i] - tv); };

    float pold = FIRST ? 0.f : p[idx];
    float qold = FIRST ? 0.f : q[idx];
    float sold = FIRST ? 0.f : s[idx];
    p[idx] = dual_up(pold, (d < Dc - 1) ? (Z(idx + HW) - zc) : 0.f, s0, ntc);
    q[idx] = dual_up(qold, (h < Hc - 1) ? (Z(idx + Wc) - zc) : 0.f, s1, ntc);
    s[idx] = dual_up(sold, (w < Wc - 1) ? (Z(idx + 1) - zc) : 0.f, s2, ntc);
}

__global__ __launch_bounds__(256) void primal_kernel(
    const float* __restrict__ t_in, const float* __restrict__ sino,
    const float* __restrict__ p, const float* __restrict__ q,
    const float* __restrict__ s,
    float* __restrict__ t_out, const float* __restrict__ sigma)
{
    const int idx = blockIdx.x * blockDim.x + threadIdx.x;
    if (idx >= NELEM_I) return;
    const int w = idx & (Wc - 1);
    const int h = (idx >> 7) & (Hc - 1);
    const int d = (idx >> 15) & (Dc - 1);

    const float tc = t_in[idx];
    const float zc = tc + LAMB * (sino[idx] - tc);

    float dt1 = ((d > 0) ? p[idx - HW] : 0.f) - ((d < Dc - 1) ? p[idx] : 0.f);
    float dt2 = ((h > 0) ? q[idx - Wc] : 0.f) - ((h < Hc - 1) ? q[idx] : 0.f);
    float dt3 = ((w > 0) ? s[idx - 1] : 0.f) - ((w < Wc - 1) ? s[idx] : 0.f);

    t_out[idx] = dt1 + dt2 + dt3 + clipf(zc, sigma[3]);
}

extern "C" void kernel_launch(void* const* d_in, const int* in_sizes, int n_in,
                              void* d_out, int out_size, void* d_ws, size_t ws_size,
                              hipStream_t stream) {
    const float* image = (const float*)d_in[0];
    const float* sino  = (const float*)d_in[1];
    const float* sigma = (const float*)d_in[2];
    const float* nt    = (const float*)d_in[3];

    float* out  = (float*)d_out;
    float* out0 = out;
    float* out1 = out + (size_t)NELEM_I;
    float* out2 = out + 2 * (size_t)NELEM_I;
    float* out3 = out + 3 * (size_t)NELEM_I;

    const size_t ARR = (size_t)NELEM_I * sizeof(float);
    dim3 block(256);
    dim3 grid(NELEM_I / 256);

    if (ws_size >= 6 * ARR) {
        // fused path: ping-pong dual buffers (A -> B)
        float* pA = (float*)d_ws;
        float* qA = pA + NELEM_I;
        float* sA = qA + NELEM_I;
        float* pB = sA + NELEM_I;
        float* qB = pB + NELEM_I;
        float* sB = qB + NELEM_I;

        cascade_fused<true, true, true><<<grid, block, 0, stream>>>(
            image, sino, nullptr, nullptr, nullptr, pA, qA, sA, out1, out0, sigma, nt, 0);
        cascade_fused<false, true, false><<<grid, block, 0, stream>>>(
            out1, sino, pA, qA, sA, pB, qB, sB, out2, nullptr, sigma, nt, 1);
        cascade_fused<false, false, false><<<grid, block, 0, stream>>>(
            out2, sino, pB, qB, sB, nullptr, nullptr, nullptr, out3, nullptr, sigma, nt, 2);
    } else {
        // split path: in-place duals, only 3 arrays of scratch needed
        float* p = (float*)d_ws;
        float* q = p + NELEM_I;
        float* s = q + NELEM_I;

        dual_kernel<true, true><<<grid, block, 0, stream>>>(image, sino, p, q, s, out0, sigma, nt, 0);
        primal_kernel<<<grid, block, 0, stream>>>(image, sino, p, q, s, out1, sigma);
        dual_kernel<false, false><<<grid, block, 0, stream>>>(out1, sino, p, q, s, nullptr, sigma, nt, 1);
        primal_kernel<<<grid, block, 0, stream>>>(out1, sino, p, q, s, out2, sigma);
        dual_kernel<false, false><<<grid, block, 0, stream>>>(out2, sino, p, q, s, nullptr, sigma, nt, 2);
        primal_kernel<<<grid, block, 0, stream>>>(out2, sino, p, q, s, out3, sigma);
    }
}

// Round 2
// 690.076 us; speedup vs baseline: 1.1189x; 1.1189x over previous
//
#include <hip/hip_runtime.h>

// Problem constants (fixed by setup_inputs): (B,D,H,W) = (2,256,256,128), fp32.
#define LAMB 0.01f
constexpr int Bc = 2, Dc = 256, Hc = 256, Wc = 128;
constexpr int HW  = Hc * Wc;               // 32768  (stride of D)
constexpr int NELEM_I = Bc * Dc * Hc * Wc; // 16,777,216
constexpr int NBLK = NELEM_I / 1024;       // 16384 blocks; 256 thr x 4 elems

__device__ __forceinline__ float clipf(float x, float s) {
    return fminf(fmaxf(x, -s), s);
}
// extrapolated dual update: pnew = clip(pold - dz, +-sg); return pnew + nt*(pnew - pold)
__device__ __forceinline__ float dual_up(float pold, float dz, float sg, float ntc) {
    float pn = clipf(pold - dz, sg);
    return pn + ntc * (pn - pold);
}
__device__ __forceinline__ float zof(float t, float s) { return t + LAMB * (s - t); }

__device__ __forceinline__ void z4(const float* __restrict__ t,
                                   const float* __restrict__ s,
                                   int i, float* out) {
    float4 a = *(const float4*)(t + i);
    float4 b = *(const float4*)(s + i);
    out[0] = zof(a.x, b.x); out[1] = zof(a.y, b.y);
    out[2] = zof(a.z, b.z); out[3] = zof(a.w, b.w);
}

// ---------------- Fused per-cascade kernel, float4 + XCD-contiguous swizzle --
template <bool FIRST, bool WRITE_PQS, bool WRITE_COPY>
__global__ __launch_bounds__(256) void cascade_v4(
    const float* __restrict__ t_in, const float* __restrict__ sino,
    const float* __restrict__ p_in, const float* __restrict__ q_in,
    const float* __restrict__ s_in,
    float* __restrict__ p_out, float* __restrict__ q_out, float* __restrict__ s_out,
    float* __restrict__ t_out, float* __restrict__ copy_out,
    const float* __restrict__ sigma, const float* __restrict__ nt, int c)
{
    // XCD swizzle: blockIdx%8 is (heuristically) the XCD; give each XCD a
    // contiguous 1/8 of the volume so plane/row halos reuse its own L2.
    const int lb = (int)(blockIdx.x & 7) * (NBLK >> 3) + (int)(blockIdx.x >> 3);
    const int i0 = (lb * 256 + (int)threadIdx.x) * 4;

    const int w0 = i0 & (Wc - 1);          // in {0,4,...,124}
    const int h  = (i0 >> 7) & (Hc - 1);
    const int d  = (i0 >> 15) & (Dc - 1);

    const float s0 = sigma[0], s1 = sigma[1], s2 = sigma[2], s3 = sigma[3];
    const float ntc = nt[c];

    const float4 tc4 = *(const float4*)(t_in + i0);
    const float4 sn4 = *(const float4*)(sino + i0);
    if (WRITE_COPY) *(float4*)(copy_out + i0) = tc4;

    // zc[1..4] = z at w0..w0+3; zc[0] = z at w0-1; zc[5] = z at w0+4
    float zc[6];
    zc[1] = zof(tc4.x, sn4.x); zc[2] = zof(tc4.y, sn4.y);
    zc[3] = zof(tc4.z, sn4.z); zc[4] = zof(tc4.w, sn4.w);
    zc[0] = (w0 > 0)      ? zof(t_in[i0 - 1], sino[i0 - 1]) : 0.f;
    zc[5] = (w0 < Wc - 4) ? zof(t_in[i0 + 4], sino[i0 + 4]) : 0.f;

    float zhp[4] = {0,0,0,0}, zhm[4] = {0,0,0,0};
    float zdp[4] = {0,0,0,0}, zdm[4] = {0,0,0,0};
    const bool hlast = (h == Hc - 1), dlast = (d == Dc - 1);
    if (!hlast) z4(t_in, sino, i0 + Wc, zhp);
    if (h > 0)  z4(t_in, sino, i0 - Wc, zhm);
    if (!dlast) z4(t_in, sino, i0 + HW, zdp);
    if (d > 0)  z4(t_in, sino, i0 - HW, zdm);

    // ---- axis D (axis=1) ----
    float pc[4], pm[4] = {0,0,0,0}, dt1[4];
    {
        float4 pv = FIRST ? make_float4(0,0,0,0) : *(const float4*)(p_in + i0);
        float po[4] = {pv.x, pv.y, pv.z, pv.w};
#pragma unroll
        for (int k = 0; k < 4; ++k)
            pc[k] = dual_up(po[k], dlast ? 0.f : (zdp[k] - zc[k + 1]), s0, ntc);
        if (d > 0) {
            float4 pmv = FIRST ? make_float4(0,0,0,0) : *(const float4*)(p_in + i0 - HW);
            float pom[4] = {pmv.x, pmv.y, pmv.z, pmv.w};
#pragma unroll
            for (int k = 0; k < 4; ++k)
                pm[k] = dual_up(pom[k], zc[k + 1] - zdm[k], s0, ntc);
        }
#pragma unroll
        for (int k = 0; k < 4; ++k)
            dt1[k] = pm[k] - (dlast ? 0.f : pc[k]);
    }

    // ---- axis H (axis=2) ----
    float qc[4], qm[4] = {0,0,0,0}, dt2[4];
    {
        float4 qv = FIRST ? make_float4(0,0,0,0) : *(const float4*)(q_in + i0);
        float qo[4] = {qv.x, qv.y, qv.z, qv.w};
#pragma unroll
        for (int k = 0; k < 4; ++k)
            qc[k] = dual_up(qo[k], hlast ? 0.f : (zhp[k] - zc[k + 1]), s1, ntc);
        if (h > 0) {
            float4 qmv = FIRST ? make_float4(0,0,0,0) : *(const float4*)(q_in + i0 - Wc);
            float qom[4] = {qmv.x, qmv.y, qmv.z, qmv.w};
#pragma unroll
            for (int k = 0; k < 4; ++k)
                qm[k] = dual_up(qom[k], zc[k + 1] - zhm[k], s1, ntc);
        }
#pragma unroll
        for (int k = 0; k < 4; ++k)
            dt2[k] = qm[k] - (hlast ? 0.f : qc[k]);
    }

    // ---- axis W (axis=3) ----
    float sc[4], dt3[4];
    {
        float4 sv = FIRST ? make_float4(0,0,0,0) : *(const float4*)(s_in + i0);
        float so[4] = {sv.x, sv.y, sv.z, sv.w};
#pragma unroll
        for (int k = 0; k < 4; ++k) {
            const bool wlast = (w0 + k == Wc - 1);          // only possible at k=3
            sc[k] = dual_up(so[k], wlast ? 0.f : (zc[k + 2] - zc[k + 1]), s2, ntc);
        }
        float smv = 0.f;                                    // s-hat at w0-1
        if (w0 > 0) {
            float som = FIRST ? 0.f : s_in[i0 - 1];
            smv = dual_up(som, zc[1] - zc[0], s2, ntc);
        }
        dt3[0] = smv - sc[0];                               // w0 <= 124 => never last
#pragma unroll
        for (int k = 1; k < 4; ++k)
            dt3[k] = sc[k - 1] - ((w0 + k == Wc - 1) ? 0.f : sc[k]);
    }

    if (WRITE_PQS) {
        *(float4*)(p_out + i0) = make_float4(pc[0], pc[1], pc[2], pc[3]);
        *(float4*)(q_out + i0) = make_float4(qc[0], qc[1], qc[2], qc[3]);
        *(float4*)(s_out + i0) = make_float4(sc[0], sc[1], sc[2], sc[3]);
    }
    float4 tn;
    tn.x = dt1[0] + dt2[0] + dt3[0] + clipf(zc[1], s3);
    tn.y = dt1[1] + dt2[1] + dt3[1] + clipf(zc[2], s3);
    tn.z = dt1[2] + dt2[2] + dt3[2] + clipf(zc[3], s3);
    tn.w = dt1[3] + dt2[3] + dt3[3] + clipf(zc[4], s3);
    *(float4*)(t_out + i0) = tn;
}

// ---------------- Fallback split path (in-place duals, 3 arrays of ws) -------
template <bool FIRST, bool WRITE_COPY>
__global__ __launch_bounds__(256) void dual_kernel(
    const float* __restrict__ t_in, const float* __restrict__ sino,
    float* p, float* q, float* s,
    float* __restrict__ copy_out,
    const float* __restrict__ sigma, const float* __restrict__ nt, int c)
{
    const int idx = blockIdx.x * blockDim.x + threadIdx.x;
    if (idx >= NELEM_I) return;
    const int w = idx & (Wc - 1);
    const int h = (idx >> 7) & (Hc - 1);
    const int d = (idx >> 15) & (Dc - 1);

    const float s0 = sigma[0], s1 = sigma[1], s2 = sigma[2];
    const float ntc = nt[c];

    const float tc = t_in[idx];
    const float zc = zof(tc, sino[idx]);
    if (WRITE_COPY) copy_out[idx] = tc;
    auto Z = [&](int i) { return zof(t_in[i], sino[i]); };

    float pold = FIRST ? 0.f : p[idx];
    float qold = FIRST ? 0.f : q[idx];
    float sold = FIRST ? 0.f : s[idx];
    p[idx] = dual_up(pold, (d < Dc - 1) ? (Z(idx + HW) - zc) : 0.f, s0, ntc);
    q[idx] = dual_up(qold, (h < Hc - 1) ? (Z(idx + Wc) - zc) : 0.f, s1, ntc);
    s[idx] = dual_up(sold, (w < Wc - 1) ? (Z(idx + 1) - zc) : 0.f, s2, ntc);
}

__global__ __launch_bounds__(256) void primal_kernel(
    const float* __restrict__ t_in, const float* __restrict__ sino,
    const float* __restrict__ p, const float* __restrict__ q,
    const float* __restrict__ s,
    float* __restrict__ t_out, const float* __restrict__ sigma)
{
    const int idx = blockIdx.x * blockDim.x + threadIdx.x;
    if (idx >= NELEM_I) return;
    const int w = idx & (Wc - 1);
    const int h = (idx >> 7) & (Hc - 1);
    const int d = (idx >> 15) & (Dc - 1);

    const float zc = zof(t_in[idx], sino[idx]);

    float dt1 = ((d > 0) ? p[idx - HW] : 0.f) - ((d < Dc - 1) ? p[idx] : 0.f);
    float dt2 = ((h > 0) ? q[idx - Wc] : 0.f) - ((h < Hc - 1) ? q[idx] : 0.f);
    float dt3 = ((w > 0) ? s[idx - 1] : 0.f) - ((w < Wc - 1) ? s[idx] : 0.f);

    t_out[idx] = dt1 + dt2 + dt3 + clipf(zc, sigma[3]);
}

extern "C" void kernel_launch(void* const* d_in, const int* in_sizes, int n_in,
                              void* d_out, int out_size, void* d_ws, size_t ws_size,
                              hipStream_t stream) {
    const float* image = (const float*)d_in[0];
    const float* sino  = (const float*)d_in[1];
    const float* sigma = (const float*)d_in[2];
    const float* nt    = (const float*)d_in[3];

    float* out  = (float*)d_out;
    float* out0 = out;
    float* out1 = out + (size_t)NELEM_I;
    float* out2 = out + 2 * (size_t)NELEM_I;
    float* out3 = out + 3 * (size_t)NELEM_I;

    const size_t ARR = (size_t)NELEM_I * sizeof(float);

    if (ws_size >= 6 * ARR) {
        // fused path: ping-pong dual buffers (A -> B)
        float* pA = (float*)d_ws;
        float* qA = pA + NELEM_I;
        float* sA = qA + NELEM_I;
        float* pB = sA + NELEM_I;
        float* qB = pB + NELEM_I;
        float* sB = qB + NELEM_I;

        dim3 block(256), grid(NBLK);
        cascade_v4<true, true, true><<<grid, block, 0, stream>>>(
            image, sino, nullptr, nullptr, nullptr, pA, qA, sA, out1, out0, sigma, nt, 0);
        cascade_v4<false, true, false><<<grid, block, 0, stream>>>(
            out1, sino, pA, qA, sA, pB, qB, sB, out2, nullptr, sigma, nt, 1);
        cascade_v4<false, false, false><<<grid, block, 0, stream>>>(
            out2, sino, pB, qB, sB, nullptr, nullptr, nullptr, out3, nullptr, sigma, nt, 2);
    } else {
        // split path: in-place duals, only 3 arrays of scratch needed
        float* p = (float*)d_ws;
        float* q = p + NELEM_I;
        float* s = q + NELEM_I;

        dim3 block(256), grid(NELEM_I / 256);
        dual_kernel<true, true><<<grid, block, 0, stream>>>(image, sino, p, q, s, out0, sigma, nt, 0);
        primal_kernel<<<grid, block, 0, stream>>>(image, sino, p, q, s, out1, sigma);
        dual_kernel<false, false><<<grid, block, 0, stream>>>(out1, sino, p, q, s, nullptr, sigma, nt, 1);
        primal_kernel<<<grid, block, 0, stream>>>(out1, sino, p, q, s, out2, sigma);
        dual_kernel<false, false><<<grid, block, 0, stream>>>(out2, sino, p, q, s, nullptr, sigma, nt, 2);
        primal_kernel<<<grid, block, 0, stream>>>(out2, sino, p, q, s, out3, sigma);
    }
}